// Round 6
// baseline (1104.400 us; speedup 1.0000x reference)
//
#include <hip/hip_runtime.h>
#include <hip/hip_cooperative_groups.h>
#include <math.h>

namespace cg = cooperative_groups;

#define NN   1000
#define DD   128
#define CTXN 130
#define NEG_BIG (-1.0e30f)

// ============================================================================
// Persistent cooperative kernel: 1024 blocks x 256 threads (4 blocks/CU
// co-resident; VGPR<=128 via launch_bounds, ~29KB LDS). Block (b, s=blk&3)
// owns emb rows [s*250, s*250+250) for ALL phases -> slice stays L2-hot.
// Phases: A mean-partials | B qproj (s==0) | C compat+local-SM+wembp
//         | D merge->g2 (s==0) | E logits | F log-softmax (s==0)
// ws: meanp[B][1024] | qpt[B][1024] | wembp[B][8192] | g2v[B][128]
//     | stats[B][128] | logits[B][1024] | mflag   (coop uses sub-strides)
// ============================================================================
__global__ __launch_bounds__(256, 4)
void coop_attn(const float* __restrict__ emb, const float* __restrict__ stepc,
               const void* __restrict__ maskp,
               const float* __restrict__ Wn, const float* __restrict__ Wf,
               const float* __restrict__ Ws, const float* __restrict__ Wo,
               float* __restrict__ out,
               float* __restrict__ meanp, float* __restrict__ qpt,
               float* __restrict__ wembp, float* __restrict__ g2v,
               float* __restrict__ stats, float* __restrict__ logits,
               int* __restrict__ mflag)
{
    cg::grid_group grid = cg::this_grid();
    const int b = blockIdx.x >> 2, s = blockIdx.x & 3;
    const int t = threadIdx.x, w = t >> 6, lane = t & 63;
    const int rg = lane >> 4, cl = lane & 15;
    const float* eb = emb + (size_t)b * (NN * DD);
    const int r0 = s * 250;

    __shared__ __align__(16) float S[7424];   // 29.7 KB, phase-unioned

    // ---------------- Phase A: column-sum partials over 250 rows ----------------
    {
        const int c4 = t & 31, g = t >> 5;    // 8 row groups
        float4 a = make_float4(0.f, 0.f, 0.f, 0.f);
        for (int r = g; r < 250; r += 8) {
            const float4 v = *(const float4*)(eb + (size_t)(r0 + r) * DD + c4 * 4);
            a.x += v.x; a.y += v.y; a.z += v.z; a.w += v.w;
        }
        ((float4*)S)[g * 32 + c4] = a;
    }
    __syncthreads();
    if (t < 128) {
        float v = 0.f;
        #pragma unroll
        for (int g = 0; g < 8; ++g) v += S[g * 128 + t];
        meanp[(size_t)b * 512 + s * 128 + t] = v;
    }
    if (blockIdx.x == 0 && t == 0) {   // mask layout probe (int32: bytes 1 mod 4 all 0)
        const unsigned char* mb8 = (const unsigned char*)maskp;
        int any = 0;
        for (int k = 0; k < 64; ++k) any |= mb8[4 * k + 1];
        *mflag = (any == 0) ? 1 : 0;
    }
    __threadfence();
    grid.sync();

    // ---------------- Phase B (s==0): mean -> query -> qproj[h][i] ----------------
    if (s == 0) {
        float* s_mean = S;         // 128
        float* s_q    = S + 128;   // 128
        float* s_r    = S + 256;   // 256
        if (t < 128) {
            float v = 0.f;
            #pragma unroll
            for (int g = 0; g < 4; ++g) v += meanp[(size_t)b * 512 + g * 128 + t];
            s_mean[t] = v * (1.0f / (float)NN);
        }
        __syncthreads();
        {
            const int d = t & 127, p = t >> 7;
            float a = 0.f;
            for (int i = 64 * p; i < 64 * p + 64; ++i)
                a = fmaf(s_mean[i], Wf[i * DD + d], a);
            const float* scb = stepc + (size_t)b * CTXN;
            const int c0 = p ? 65 : 0, c1 = p ? 130 : 65;
            for (int c = c0; c < c1; ++c)
                a = fmaf(scb[c], Ws[c * DD + d], a);
            s_r[p * 128 + d] = a;
        }
        __syncthreads();
        if (t < 128) s_q[t] = s_r[t] + s_r[128 + t];
        __syncthreads();
        {
            const int i = t & 127, p = t >> 7;
            #pragma unroll
            for (int u = 0; u < 4; ++u) {
                const int h = p + 2 * u;
                float a = 0.f;
                #pragma unroll
                for (int j = 0; j < 16; ++j)
                    a = fmaf(Wn[i * 384 + h * 16 + j], s_q[h * 16 + j], a);
                qpt[(size_t)b * 1024 + h * 128 + i] = a * 0.25f;
            }
        }
    }
    __threadfence();
    grid.sync();

    // ---------------- Phase C: compat + slice-local softmax + wembp ----------------
    {
        float* s_qpT  = S;          // 1024
        float* s_cp   = S + 1024;   // 2000: compat -> p in place
        float* s_m    = S + 3024;   // 8
        float* s_sum  = S + 3032;   // 8
        float* s_part = S + 3040;   // 4224: [w][h][132]
        for (int i = t; i < 1024; i += 256) s_qpT[i] = qpt[(size_t)b * 1024 + i];
        __syncthreads();
        float4 qa[8], qb[8];   // qproj cols cl*8..cl*8+7, all 8 heads (64 VGPR)
        #pragma unroll
        for (int h = 0; h < 8; ++h) {
            qa[h] = *(const float4*)&s_qpT[h * 128 + cl * 8];
            qb[h] = *(const float4*)&s_qpT[h * 128 + cl * 8 + 4];
        }
        const int use32 = *mflag;
        const unsigned char* mk8 = (const unsigned char*)maskp + (size_t)b * NN;
        const int* mk32 = (const int*)maskp + (size_t)b * NN;
        for (int it = 0; it < 16; ++it) {   // 4 waves x 4 rows x 16 = 256 >= 250
            const int r = it * 16 + w * 4 + rg;
            float acc[8] = {0.f,0.f,0.f,0.f,0.f,0.f,0.f,0.f};
            if (r < 250) {
                const float4 e0 = *(const float4*)(eb + (size_t)(r0 + r) * DD + cl * 8);
                const float4 e1 = *(const float4*)(eb + (size_t)(r0 + r) * DD + cl * 8 + 4);
                #pragma unroll
                for (int h = 0; h < 8; ++h) {
                    float a = e0.x * qa[h].x;
                    a = fmaf(e0.y, qa[h].y, a);
                    a = fmaf(e0.z, qa[h].z, a);
                    a = fmaf(e0.w, qa[h].w, a);
                    a = fmaf(e1.x, qb[h].x, a);
                    a = fmaf(e1.y, qb[h].y, a);
                    a = fmaf(e1.z, qb[h].z, a);
                    a = fmaf(e1.w, qb[h].w, a);
                    acc[h] = a;
                }
            }
            #pragma unroll
            for (int h = 0; h < 8; ++h) {
                acc[h] += __shfl_xor(acc[h], 1, 16);
                acc[h] += __shfl_xor(acc[h], 2, 16);
                acc[h] += __shfl_xor(acc[h], 4, 16);
                acc[h] += __shfl_xor(acc[h], 8, 16);
            }
            if (cl == 0 && r < 250) {
                const int n = r0 + r;
                const bool m = use32 ? (mk32[n] != 0) : (mk8[n] != 0);
                float4 o0, o1;
                if (m) { o0 = make_float4(NEG_BIG, NEG_BIG, NEG_BIG, NEG_BIG); o1 = o0; }
                else   { o0 = make_float4(acc[0], acc[1], acc[2], acc[3]);
                         o1 = make_float4(acc[4], acc[5], acc[6], acc[7]); }
                *(float4*)&s_cp[r * 8]     = o0;
                *(float4*)&s_cp[r * 8 + 4] = o1;
            }
        }
        __syncthreads();
        // local per-head max / raw sum: wave w -> heads w and w+4
        #pragma unroll
        for (int hh = 0; hh < 2; ++hh) {
            const int h = w + 4 * hh;
            float m = NEG_BIG;
            for (int r = lane; r < 250; r += 64) m = fmaxf(m, s_cp[r * 8 + h]);
            #pragma unroll
            for (int o = 32; o; o >>= 1) m = fmaxf(m, __shfl_xor(m, o, 64));
            float su = 0.f;
            for (int r = lane; r < 250; r += 64) su += expf(s_cp[r * 8 + h] - m);
            #pragma unroll
            for (int o = 32; o; o >>= 1) su += __shfl_xor(su, o, 64);
            if (lane == 0) { s_m[h] = m; s_sum[h] = su; }
        }
        __syncthreads();
        for (int idx = t; idx < 2000; idx += 256)
            s_cp[idx] = expf(s_cp[idx] - s_m[idx & 7]);   // unnormalized p
        __syncthreads();
        {   // outer product (2nd slice read, L2-hot): lane owns cols 2l,2l+1
            float a0[8] = {0,0,0,0,0,0,0,0}, a1[8] = {0,0,0,0,0,0,0,0};
            for (int r = w; r < 250; r += 4) {
                const float2 e  = *(const float2*)(eb + (size_t)(r0 + r) * DD + 2 * lane);
                const float4 p0 = *(const float4*)&s_cp[r * 8];
                const float4 p1 = *(const float4*)&s_cp[r * 8 + 4];
                a0[0] = fmaf(e.x, p0.x, a0[0]); a1[0] = fmaf(e.y, p0.x, a1[0]);
                a0[1] = fmaf(e.x, p0.y, a0[1]); a1[1] = fmaf(e.y, p0.y, a1[1]);
                a0[2] = fmaf(e.x, p0.z, a0[2]); a1[2] = fmaf(e.y, p0.z, a1[2]);
                a0[3] = fmaf(e.x, p0.w, a0[3]); a1[3] = fmaf(e.y, p0.w, a1[3]);
                a0[4] = fmaf(e.x, p1.x, a0[4]); a1[4] = fmaf(e.y, p1.x, a1[4]);
                a0[5] = fmaf(e.x, p1.y, a0[5]); a1[5] = fmaf(e.y, p1.y, a1[5]);
                a0[6] = fmaf(e.x, p1.z, a0[6]); a1[6] = fmaf(e.y, p1.z, a1[6]);
                a0[7] = fmaf(e.x, p1.w, a0[7]); a1[7] = fmaf(e.y, p1.w, a1[7]);
            }
            #pragma unroll
            for (int h = 0; h < 8; ++h)
                *(float2*)&s_part[(w * 8 + h) * 132 + 2 * lane] = make_float2(a0[h], a1[h]);
        }
        __syncthreads();
        for (int idx = t; idx < 1024; idx += 256) {
            const int h = idx >> 7, i = idx & 127;
            float v = 0.f;
            #pragma unroll
            for (int g = 0; g < 4; ++g) v += s_part[(g * 8 + h) * 132 + i];
            wembp[(size_t)b * 4096 + s * 1024 + idx] = v;   // [b][s][h][i]
        }
        if (t < 8)       stats[(size_t)b * 64 + s * 16 + t] = s_m[t];
        else if (t < 16) stats[(size_t)b * 64 + s * 16 + t] = s_sum[t - 8];
    }
    __threadfence();
    grid.sync();

    // ---------------- Phase D (s==0): merge -> wemb -> heads -> glimpse -> g2 ----------------
    if (s == 0) {
        float* s_w    = S;          // 32 [s][h]
        float* s_wemb = S + 32;     // 1040 [h][130]
        float* s_r    = S + 1072;   // 256
        float* s_h    = S + 1328;   // 128
        float* s_gl   = S + 1456;   // 128
        if (t < 8) {
            const int h = t;
            float m = NEG_BIG;
            #pragma unroll
            for (int ss = 0; ss < 4; ++ss) m = fmaxf(m, stats[(size_t)b * 64 + ss * 16 + h]);
            float den = 0.f;
            #pragma unroll
            for (int ss = 0; ss < 4; ++ss)
                den += stats[(size_t)b * 64 + ss * 16 + 8 + h] * expf(stats[(size_t)b * 64 + ss * 16 + h] - m);
            const float dinv = 1.0f / den;
            #pragma unroll
            for (int ss = 0; ss < 4; ++ss)
                s_w[ss * 8 + h] = expf(stats[(size_t)b * 64 + ss * 16 + h] - m) * dinv;
        }
        __syncthreads();
        for (int idx = t; idx < 1024; idx += 256) {
            const int h = idx >> 7, i = idx & 127;
            float v = 0.f;
            #pragma unroll
            for (int ss = 0; ss < 4; ++ss)
                v += wembp[(size_t)b * 4096 + ss * 1024 + idx] * s_w[ss * 8 + h];
            s_wemb[h * 130 + i] = v;
        }
        __syncthreads();
        {   // heads[j] = sum_i Wv[i,j] wemb[j>>4][i]
            const int j = t & 127, p = t >> 7;
            float a = 0.f;
            for (int i = 64 * p; i < 64 * p + 64; ++i)
                a = fmaf(Wn[i * 384 + 128 + j], s_wemb[(j >> 4) * 130 + i], a);
            s_r[p * 128 + j] = a;
        }
        __syncthreads();
        if (t < 128) s_h[t] = s_r[t] + s_r[128 + t];
        __syncthreads();
        {   // glimpse[d] = sum_j heads[j] Wo[j,d]
            const int d = t & 127, p = t >> 7;
            float a = 0.f;
            for (int j = 64 * p; j < 64 * p + 64; ++j)
                a = fmaf(s_h[j], Wo[j * DD + d], a);
            s_r[p * 128 + d] = a;
        }
        __syncthreads();
        if (t < 128) s_gl[t] = s_r[t] + s_r[128 + t];
        __syncthreads();
        {   // g2[i] = (1/sqrt(128)) sum_d Wl[i,d] glimpse[d]
            const int i = t & 127, p = t >> 7;
            float a = 0.f;
            for (int d = 64 * p; d < 64 * p + 64; ++d)
                a = fmaf(Wn[i * 384 + 256 + d], s_gl[d], a);
            s_r[p * 128 + i] = a;
        }
        __syncthreads();
        if (t < 128)
            g2v[(size_t)b * 128 + t] = (s_r[t] + s_r[128 + t]) * 0.08838834764831845f;
    }
    __threadfence();
    grid.sync();

    // ---------------- Phase E: logits (3rd slice read, L2-hot) ----------------
    {
        if (t < 128) S[t] = g2v[(size_t)b * 128 + t];
        __syncthreads();
        const float4 ga = *(const float4*)&S[cl * 8];
        const float4 gb = *(const float4*)&S[cl * 8 + 4];
        const int use32 = *mflag;
        const unsigned char* mk8 = (const unsigned char*)maskp + (size_t)b * NN;
        const int* mk32 = (const int*)maskp + (size_t)b * NN;
        for (int it = 0; it < 16; ++it) {
            const int r = it * 16 + w * 4 + rg;
            float a = 0.f;
            if (r < 250) {
                const float4 e0 = *(const float4*)(eb + (size_t)(r0 + r) * DD + cl * 8);
                const float4 e1 = *(const float4*)(eb + (size_t)(r0 + r) * DD + cl * 8 + 4);
                a = e0.x * ga.x;
                a = fmaf(e0.y, ga.y, a);
                a = fmaf(e0.z, ga.z, a);
                a = fmaf(e0.w, ga.w, a);
                a = fmaf(e1.x, gb.x, a);
                a = fmaf(e1.y, gb.y, a);
                a = fmaf(e1.z, gb.z, a);
                a = fmaf(e1.w, gb.w, a);
            }
            a += __shfl_xor(a, 1, 16);
            a += __shfl_xor(a, 2, 16);
            a += __shfl_xor(a, 4, 16);
            a += __shfl_xor(a, 8, 16);
            if (cl == 0 && r < 250) {
                const int n = r0 + r;
                const bool m = use32 ? (mk32[n] != 0) : (mk8[n] != 0);
                logits[(size_t)b * 1024 + n] = m ? NEG_BIG : 10.0f * tanhf(a);
            }
        }
    }
    __threadfence();
    grid.sync();

    // ---------------- Phase F (s==0): log_softmax + store ----------------
    if (s == 0) {
        const float* lg = logits + (size_t)b * 1024;
        float m = NEG_BIG;
        for (int n = t; n < NN; n += 256) m = fmaxf(m, lg[n]);
        #pragma unroll
        for (int o = 32; o; o >>= 1) m = fmaxf(m, __shfl_xor(m, o, 64));
        if (lane == 0) S[w] = m;
        __syncthreads();
        if (t == 0) S[4] = fmaxf(fmaxf(S[0], S[1]), fmaxf(S[2], S[3]));
        __syncthreads();
        const float mb = S[4];
        float sum = 0.f;
        for (int n = t; n < NN; n += 256) sum += expf(lg[n] - mb);
        #pragma unroll
        for (int o = 32; o; o >>= 1) sum += __shfl_xor(sum, o, 64);
        if (lane == 0) S[8 + w] = sum;
        __syncthreads();
        if (t == 0) S[5] = mb + logf(S[8] + S[9] + S[10] + S[11]);
        __syncthreads();
        const float lse = S[5];
        float* ob = out + (size_t)b * NN;
        for (int n = t; n < NN; n += 256) ob[n] = lg[n] - lse;
    }
}

// ============================================================================
// Fallback pipeline (round-5, proven 134 us) — used if coop launch fails.
// ============================================================================
__global__ __launch_bounds__(256, 8)
void k1_meanpart(const float* __restrict__ emb, float* __restrict__ meanp) {
    const int b = blockIdx.x >> 3, s = blockIdx.x & 7;
    const int t = threadIdx.x;
    const float* eb = emb + (size_t)b * (NN * DD);
    __shared__ __align__(16) float s_red[8 * 128];
    const int c4 = t & 31, rg = t >> 5;
    float4 a = make_float4(0.f, 0.f, 0.f, 0.f);
    for (int nl = rg; nl < 125; nl += 8) {
        const float4 v = *(const float4*)(eb + (size_t)(s * 125 + nl) * DD + c4 * 4);
        a.x += v.x; a.y += v.y; a.z += v.z; a.w += v.w;
    }
    ((float4*)s_red)[rg * 32 + c4] = a;
    __syncthreads();
    if (t < 128) {
        float v = 0.f;
        #pragma unroll
        for (int g = 0; g < 8; ++g) v += s_red[g * 128 + t];
        meanp[(size_t)b * 1024 + s * 128 + t] = v;
    }
}

__global__ __launch_bounds__(512, 4)
void k1b_qproj(const float* __restrict__ meanp, const float* __restrict__ stepc,
               const void* __restrict__ maskp,
               const float* __restrict__ Wn, const float* __restrict__ Wf,
               const float* __restrict__ Ws,
               float* __restrict__ qpt, int* __restrict__ mflag) {
    const int b = blockIdx.x, t = threadIdx.x;
    __shared__ float s_mean[128], s_q[128];
    __shared__ float s_red[512];
    if (b == 0 && t == 0) {
        const unsigned char* mb8 = (const unsigned char*)maskp;
        int any = 0;
        for (int k = 0; k < 64; ++k) any |= mb8[4 * k + 1];
        *mflag = (any == 0) ? 1 : 0;
    }
    if (t < 128) {
        float v = 0.f;
        #pragma unroll
        for (int g = 0; g < 8; ++g) v += meanp[(size_t)b * 1024 + g * 128 + t];
        s_mean[t] = v * (1.0f / (float)NN);
    }
    __syncthreads();
    {
        const int d = t & 127, p = t >> 7;
        float a = 0.f;
        for (int i = 32 * p; i < 32 * p + 32; ++i)
            a = fmaf(s_mean[i], Wf[i * DD + d], a);
        const float* scb = stepc + (size_t)b * CTXN;
        const int c0 = 32 * p, c1 = (p == 3) ? CTXN : 32 * p + 32;
        for (int c = c0; c < c1; ++c)
            a = fmaf(scb[c], Ws[c * DD + d], a);
        s_red[p * 128 + d] = a;
    }
    __syncthreads();
    if (t < 128) s_q[t] = s_red[t] + s_red[128 + t] + s_red[256 + t] + s_red[384 + t];
    __syncthreads();
    {
        const int i = t & 127, p = t >> 7;
        #pragma unroll
        for (int u = 0; u < 2; ++u) {
            const int h = p + 4 * u;
            float a = 0.f;
            #pragma unroll
            for (int j = 0; j < 16; ++j)
                a = fmaf(Wn[i * 384 + h * 16 + j], s_q[h * 16 + j], a);
            qpt[(size_t)b * 1024 + h * 128 + i] = a * 0.25f;
        }
    }
}

__global__ __launch_bounds__(512, 2)
void kB_fused(const float* __restrict__ emb, const float* __restrict__ qpt,
              const void* __restrict__ maskp, const int* __restrict__ mflag,
              float* __restrict__ wembp, float* __restrict__ stats) {
    const int b = blockIdx.x >> 3, s = blockIdx.x & 7;
    const int t = threadIdx.x, w = t >> 6, lane = t & 63;
    const int rg = lane >> 4, cl = lane & 15;
    const float* eb = emb + (size_t)b * (NN * DD);
    __shared__ __align__(16) float s_qpT[1024];
    __shared__ __align__(16) float s_compat[128 * 8];
    __shared__ __align__(16) float s_p[128 * 8];
    __shared__ float s_m[8], s_sum[8];
    __shared__ float s_part[8 * 8 * 132];
    for (int i = t; i < 1024; i += 512) s_qpT[i] = qpt[(size_t)b * 1024 + i];
    __syncthreads();
    float4 qa[8], qb[8];
    #pragma unroll
    for (int h = 0; h < 8; ++h) {
        qa[h] = *(const float4*)&s_qpT[h * 128 + cl * 8];
        qb[h] = *(const float4*)&s_qpT[h * 128 + cl * 8 + 4];
    }
    const int use32 = *mflag;
    const unsigned char* mk8 = (const unsigned char*)maskp + (size_t)b * NN;
    const int* mk32 = (const int*)maskp + (size_t)b * NN;
    #pragma unroll
    for (int it = 0; it < 4; ++it) {
        const int r = w * 16 + it * 4 + rg;
        const int n = s * 125 + r;
        float acc[8] = {0.f,0.f,0.f,0.f,0.f,0.f,0.f,0.f};
        if (r < 125) {
            const float4 e0 = *(const float4*)(eb + (size_t)n * DD + cl * 8);
            const float4 e1 = *(const float4*)(eb + (size_t)n * DD + cl * 8 + 4);
            #pragma unroll
            for (int h = 0; h < 8; ++h) {
                float a = e0.x * qa[h].x;
                a = fmaf(e0.y, qa[h].y, a);
                a = fmaf(e0.z, qa[h].z, a);
                a = fmaf(e0.w, qa[h].w, a);
                a = fmaf(e1.x, qb[h].x, a);
                a = fmaf(e1.y, qb[h].y, a);
                a = fmaf(e1.z, qb[h].z, a);
                a = fmaf(e1.w, qb[h].w, a);
                acc[h] = a;
            }
        }
        #pragma unroll
        for (int h = 0; h < 8; ++h) {
            acc[h] += __shfl_xor(acc[h], 1, 16);
            acc[h] += __shfl_xor(acc[h], 2, 16);
            acc[h] += __shfl_xor(acc[h], 4, 16);
            acc[h] += __shfl_xor(acc[h], 8, 16);
        }
        if (cl == 0 && r < 125) {
            const bool m = use32 ? (mk32[n] != 0) : (mk8[n] != 0);
            float4 o0, o1;
            if (m) { o0 = make_float4(NEG_BIG, NEG_BIG, NEG_BIG, NEG_BIG); o1 = o0; }
            else   { o0 = make_float4(acc[0], acc[1], acc[2], acc[3]);
                     o1 = make_float4(acc[4], acc[5], acc[6], acc[7]); }
            *(float4*)&s_compat[r * 8]     = o0;
            *(float4*)&s_compat[r * 8 + 4] = o1;
        }
    }
    __syncthreads();
    {
        float m = NEG_BIG;
        for (int r = lane; r < 125; r += 64) m = fmaxf(m, s_compat[r * 8 + w]);
        #pragma unroll
        for (int o = 32; o; o >>= 1) m = fmaxf(m, __shfl_xor(m, o, 64));
        float sum = 0.f;
        for (int r = lane; r < 125; r += 64) sum += expf(s_compat[r * 8 + w] - m);
        #pragma unroll
        for (int o = 32; o; o >>= 1) sum += __shfl_xor(sum, o, 64);
        if (lane == 0) { s_m[w] = m; s_sum[w] = sum; }
    }
    __syncthreads();
    for (int idx = t; idx < 1000; idx += 512)
        s_p[idx] = expf(s_compat[idx] - s_m[idx & 7]);
    __syncthreads();
    {
        float a0[8] = {0,0,0,0,0,0,0,0}, a1[8] = {0,0,0,0,0,0,0,0};
        for (int nl = w; nl < 125; nl += 8) {
            const float2 e  = *(const float2*)(eb + (size_t)(s * 125 + nl) * DD + 2 * lane);
            const float4 p0 = *(const float4*)&s_p[nl * 8];
            const float4 p1 = *(const float4*)&s_p[nl * 8 + 4];
            a0[0] = fmaf(e.x, p0.x, a0[0]); a1[0] = fmaf(e.y, p0.x, a1[0]);
            a0[1] = fmaf(e.x, p0.y, a0[1]); a1[1] = fmaf(e.y, p0.y, a1[1]);
            a0[2] = fmaf(e.x, p0.z, a0[2]); a1[2] = fmaf(e.y, p0.z, a1[2]);
            a0[3] = fmaf(e.x, p0.w, a0[3]); a1[3] = fmaf(e.y, p0.w, a1[3]);
            a0[4] = fmaf(e.x, p1.x, a0[4]); a1[4] = fmaf(e.y, p1.x, a1[4]);
            a0[5] = fmaf(e.x, p1.y, a0[5]); a1[5] = fmaf(e.y, p1.y, a1[5]);
            a0[6] = fmaf(e.x, p1.z, a0[6]); a1[6] = fmaf(e.y, p1.z, a1[6]);
            a0[7] = fmaf(e.x, p1.w, a0[7]); a1[7] = fmaf(e.y, p1.w, a1[7]);
        }
        #pragma unroll
        for (int h = 0; h < 8; ++h)
            *(float2*)&s_part[(w * 8 + h) * 132 + 2 * lane] = make_float2(a0[h], a1[h]);
    }
    __syncthreads();
    for (int idx = t; idx < 1024; idx += 512) {
        const int h = idx >> 7, i = idx & 127;
        float v = 0.f;
        #pragma unroll
        for (int g = 0; g < 8; ++g) v += s_part[(g * 8 + h) * 132 + i];
        wembp[(size_t)b * 8192 + s * 1024 + idx] = v;
    }
    if (t < 8)        stats[(size_t)b * 128 + s * 16 + t] = s_m[t];
    else if (t < 16)  stats[(size_t)b * 128 + s * 16 + t] = s_sum[t - 8];
}

__global__ __launch_bounds__(512, 4)
void k4a_g2(const float* __restrict__ wembp, const float* __restrict__ stats,
            const float* __restrict__ Wn, const float* __restrict__ Wo,
            float* __restrict__ g2v) {
    const int b = blockIdx.x, t = threadIdx.x;
    __shared__ float s_w[8][8];
    __shared__ float s_wemb[8 * 130];
    __shared__ float s_red[512];
    __shared__ float s_heads[128], s_gl[128];
    if (t < 8) {
        const int h = t;
        float m = NEG_BIG;
        #pragma unroll
        for (int s = 0; s < 8; ++s) m = fmaxf(m, stats[(size_t)b * 128 + s * 16 + h]);
        float den = 0.f;
        #pragma unroll
        for (int s = 0; s < 8; ++s)
            den += stats[(size_t)b * 128 + s * 16 + 8 + h] * expf(stats[(size_t)b * 128 + s * 16 + h] - m);
        const float dinv = 1.0f / den;
        #pragma unroll
        for (int s = 0; s < 8; ++s)
            s_w[s][h] = expf(stats[(size_t)b * 128 + s * 16 + h] - m) * dinv;
    }
    __syncthreads();
    for (int idx = t; idx < 1024; idx += 512) {
        const int h = idx >> 7, i = idx & 127;
        float v = 0.f;
        #pragma unroll
        for (int s = 0; s < 8; ++s) v += wembp[(size_t)b * 8192 + s * 1024 + idx] * s_w[s][h];
        s_wemb[h * 130 + i] = v;
    }
    __syncthreads();
    {
        const int j = t & 127, p = t >> 7;
        float a = 0.f;
        for (int i = 32 * p; i < 32 * p + 32; ++i)
            a = fmaf(Wn[i * 384 + 128 + j], s_wemb[(j >> 4) * 130 + i], a);
        s_red[p * 128 + j] = a;
    }
    __syncthreads();
    if (t < 128) s_heads[t] = s_red[t] + s_red[128 + t] + s_red[256 + t] + s_red[384 + t];
    __syncthreads();
    {
        const int d = t & 127, p = t >> 7;
        float a = 0.f;
        for (int j = 32 * p; j < 32 * p + 32; ++j)
            a = fmaf(s_heads[j], Wo[j * DD + d], a);
        s_red[p * 128 + d] = a;
    }
    __syncthreads();
    if (t < 128) s_gl[t] = s_red[t] + s_red[128 + t] + s_red[256 + t] + s_red[384 + t];
    __syncthreads();
    {
        const int i = t & 127, p = t >> 7;
        float a = 0.f;
        for (int d = 32 * p; d < 32 * p + 32; ++d)
            a = fmaf(Wn[i * 384 + 256 + d], s_gl[d], a);
        s_red[p * 128 + i] = a;
    }
    __syncthreads();
    if (t < 128)
        g2v[(size_t)b * 128 + t] =
            (s_red[t] + s_red[128 + t] + s_red[256 + t] + s_red[384 + t]) * 0.08838834764831845f;
}

__global__ __launch_bounds__(512, 2)
void k4b_logits(const float* __restrict__ emb, const float* __restrict__ g2v,
                const void* __restrict__ maskp, const int* __restrict__ mflag,
                float* __restrict__ logits) {
    const int b = blockIdx.x >> 3, s = blockIdx.x & 7;
    const int t = threadIdx.x, w = t >> 6, lane = t & 63;
    const int rg = lane >> 4, cl = lane & 15;
    const float* eb = emb + (size_t)b * (NN * DD);
    __shared__ __align__(16) float s_g2[128];
    if (t < 128) s_g2[t] = g2v[(size_t)b * 128 + t];
    __syncthreads();
    const float4 ga = *(const float4*)&s_g2[cl * 8];
    const float4 gb = *(const float4*)&s_g2[cl * 8 + 4];
    const int use32 = *mflag;
    const unsigned char* mk8 = (const unsigned char*)maskp + (size_t)b * NN;
    const int* mk32 = (const int*)maskp + (size_t)b * NN;
    #pragma unroll
    for (int it = 0; it < 4; ++it) {
        const int r = w * 16 + it * 4 + rg;
        const int n = s * 125 + r;
        float a = 0.f;
        if (r < 125) {
            const float4 e0 = *(const float4*)(eb + (size_t)n * DD + cl * 8);
            const float4 e1 = *(const float4*)(eb + (size_t)n * DD + cl * 8 + 4);
            a = e0.x * ga.x;
            a = fmaf(e0.y, ga.y, a);
            a = fmaf(e0.z, ga.z, a);
            a = fmaf(e0.w, ga.w, a);
            a = fmaf(e1.x, gb.x, a);
            a = fmaf(e1.y, gb.y, a);
            a = fmaf(e1.z, gb.z, a);
            a = fmaf(e1.w, gb.w, a);
        }
        a += __shfl_xor(a, 1, 16);
        a += __shfl_xor(a, 2, 16);
        a += __shfl_xor(a, 4, 16);
        a += __shfl_xor(a, 8, 16);
        if (cl == 0 && r < 125) {
            const bool m = use32 ? (mk32[n] != 0) : (mk8[n] != 0);
            logits[(size_t)b * 1024 + n] = m ? NEG_BIG : 10.0f * tanhf(a);
        }
    }
}

__global__ __launch_bounds__(512, 4)
void k5_logsoftmax(const float* __restrict__ logits, float* __restrict__ out) {
    const int b = blockIdx.x, t = threadIdx.x, w = t >> 6, lane = t & 63;
    __shared__ float s_red[16];
    __shared__ float s_lse;
    const float* lg = logits + (size_t)b * 1024;
    float m = NEG_BIG;
    for (int n = t; n < NN; n += 512) m = fmaxf(m, lg[n]);
    #pragma unroll
    for (int o = 32; o; o >>= 1) m = fmaxf(m, __shfl_xor(m, o, 64));
    if (lane == 0) s_red[w] = m;
    __syncthreads();
    if (t == 0) {
        float mm = s_red[0];
        #pragma unroll
        for (int i = 1; i < 8; ++i) mm = fmaxf(mm, s_red[i]);
        s_red[8] = mm;
    }
    __syncthreads();
    const float mb = s_red[8];
    float sum = 0.f;
    for (int n = t; n < NN; n += 512) sum += expf(lg[n] - mb);
    #pragma unroll
    for (int o = 32; o; o >>= 1) sum += __shfl_xor(sum, o, 64);
    __syncthreads();
    if (lane == 0) s_red[w] = sum;
    __syncthreads();
    if (t == 0) {
        float ss = 0.f;
        #pragma unroll
        for (int i = 0; i < 8; ++i) ss += s_red[i];
        s_lse = mb + logf(ss);
    }
    __syncthreads();
    const float lse = s_lse;
    float* ob = out + (size_t)b * NN;
    for (int n = t; n < NN; n += 512) ob[n] = lg[n] - lse;
}

extern "C" void kernel_launch(void* const* d_in, const int* in_sizes, int n_in,
                              void* d_out, int out_size, void* d_ws, size_t ws_size,
                              hipStream_t stream) {
    const float* emb   = (const float*)d_in[0];
    const float* stepc = (const float*)d_in[1];
    const void*  mask  = (const void*)d_in[2];
    const float* Wn = (const float*)d_in[3];
    const float* Wf = (const float*)d_in[4];
    const float* Ws = (const float*)d_in[5];
    const float* Wo = (const float*)d_in[6];
    float* out = (float*)d_out;
    const int B = in_sizes[0] / (NN * DD);  // 256

    // pipeline-superset ws layout (coop uses sub-strides of the same regions)
    float* wsf = (float*)d_ws;
    const size_t n_meanp = (size_t)B * 1024;
    const size_t n_qpt   = (size_t)B * 1024;
    const size_t n_wembp = (size_t)B * 8192;
    const size_t n_g2    = (size_t)B * 128;
    const size_t n_stats = (size_t)B * 128;
    const size_t n_logit = (size_t)B * 1024;
    const size_t need = (n_meanp + n_qpt + n_wembp + n_g2 + n_stats + n_logit + 16) * sizeof(float);
    if (ws_size < need) return;  // cannot run (harness always provides ample ws)

    float* meanp  = wsf;
    float* qpt    = meanp + n_meanp;
    float* wembp  = qpt + n_qpt;
    float* g2v    = wembp + n_wembp;
    float* stats  = g2v + n_g2;
    float* logits = stats + n_stats;
    int*   mflag  = (int*)(logits + n_logit);

    // ---- preferred: single persistent cooperative kernel ----
    {
        void* args[] = { (void*)&emb, (void*)&stepc, (void*)&mask,
                         (void*)&Wn, (void*)&Wf, (void*)&Ws, (void*)&Wo,
                         (void*)&out, (void*)&meanp, (void*)&qpt, (void*)&wembp,
                         (void*)&g2v, (void*)&stats, (void*)&logits, (void*)&mflag };
        hipError_t e = hipLaunchCooperativeKernel((const void*)coop_attn,
                                                  dim3(B * 4), dim3(256),
                                                  args, 0, stream);
        if (e == hipSuccess) return;
    }

    // ---- fallback: proven 6-kernel pipeline ----
    k1_meanpart  <<<B * 8, 256, 0, stream>>>(emb, meanp);
    k1b_qproj    <<<B,     512, 0, stream>>>(meanp, stepc, mask, Wn, Wf, Ws, qpt, mflag);
    kB_fused     <<<B * 8, 512, 0, stream>>>(emb, qpt, mask, mflag, wembp, stats);
    k4a_g2       <<<B,     512, 0, stream>>>(wembp, stats, Wn, Wo, g2v);
    k4b_logits   <<<B * 8, 512, 0, stream>>>(emb, g2v, mask, mflag, logits);
    k5_logsoftmax<<<B,     512, 0, stream>>>(logits, out);
}

// Round 7
// 130.037 us; speedup vs baseline: 8.4930x; 8.4930x over previous
//
#include <hip/hip_runtime.h>
#include <math.h>

#define NN   1000
#define DD   128
#define CTXN 130
#define NEG_BIG (-1.0e30f)

// ============================================================================
// Pipeline (emb read once per streaming kernel; kB keeps its slice in LDS):
//  k1  (B*8): per-slice column sums                       (emb pass 1)
//  k1b (B)  : mean -> query -> qproj[h][i], mask probe
//  kB  (B*8): compat -> local max/sum -> wembp_s          (emb pass 2, single read,
//             slice teed into LDS and reused for the attn.emb outer product)
//  k4a (B)  : rescale-merge slices -> wemb -> heads -> glimpse -> g2
//  k4b (B*8): logits[n] = 10*tanh(emb_n . g2)             (emb pass 3)
//  k5  (B)  : log_softmax
// ws: meanp[B][1024] | qpt[B][1024] | wembp[B][8192] | g2v[B][128]
//     | stats[B][128] | logits[B][1024] | mflag
// ============================================================================

// ---------------- K1: per-(b,s) partial column sums ----------------
__global__ __launch_bounds__(256, 8)
void k1_meanpart(const float* __restrict__ emb, float* __restrict__ meanp) {
    const int b = blockIdx.x >> 3, s = blockIdx.x & 7;
    const int t = threadIdx.x;
    const float* eb = emb + (size_t)b * (NN * DD);
    __shared__ __align__(16) float s_red[8 * 128];
    const int c4 = t & 31, rg = t >> 5;
    float4 a = make_float4(0.f, 0.f, 0.f, 0.f);
    for (int nl = rg; nl < 125; nl += 8) {
        const float4 v = *(const float4*)(eb + (size_t)(s * 125 + nl) * DD + c4 * 4);
        a.x += v.x; a.y += v.y; a.z += v.z; a.w += v.w;
    }
    ((float4*)s_red)[rg * 32 + c4] = a;
    __syncthreads();
    if (t < 128) {
        float v = 0.f;
        #pragma unroll
        for (int g = 0; g < 8; ++g) v += s_red[g * 128 + t];
        meanp[(size_t)b * 1024 + s * 128 + t] = v;
    }
}

// ---------------- K1b: mean -> query -> qproj [h][i], + mask layout probe ----------------
__global__ __launch_bounds__(512, 4)
void k1b_qproj(const float* __restrict__ meanp, const float* __restrict__ stepc,
               const void* __restrict__ maskp,
               const float* __restrict__ Wn, const float* __restrict__ Wf,
               const float* __restrict__ Ws,
               float* __restrict__ qpt, int* __restrict__ mflag) {
    const int b = blockIdx.x, t = threadIdx.x;
    __shared__ float s_mean[128], s_q[128];
    __shared__ float s_red[512];
    if (b == 0 && t == 0) {   // int32 mask: bytes at 1 mod 4 are always 0
        const unsigned char* mb8 = (const unsigned char*)maskp;
        int any = 0;
        for (int k = 0; k < 64; ++k) any |= mb8[4 * k + 1];
        *mflag = (any == 0) ? 1 : 0;
    }
    if (t < 128) {
        float v = 0.f;
        #pragma unroll
        for (int g = 0; g < 8; ++g) v += meanp[(size_t)b * 1024 + g * 128 + t];
        s_mean[t] = v * (1.0f / (float)NN);
    }
    __syncthreads();
    {   // query[d] = sum_i mean[i] Wf[i,d] + sum_c sc[c] Ws[c,d]
        const int d = t & 127, p = t >> 7;
        float a = 0.f;
        for (int i = 32 * p; i < 32 * p + 32; ++i)
            a = fmaf(s_mean[i], Wf[i * DD + d], a);
        const float* scb = stepc + (size_t)b * CTXN;
        const int c0 = 32 * p, c1 = (p == 3) ? CTXN : 32 * p + 32;
        for (int c = c0; c < c1; ++c)
            a = fmaf(scb[c], Ws[c * DD + d], a);
        s_red[p * 128 + d] = a;
    }
    __syncthreads();
    if (t < 128) s_q[t] = s_red[t] + s_red[128 + t] + s_red[256 + t] + s_red[384 + t];
    __syncthreads();
    {   // qpt[b][h][i] = 0.25 * sum_j Wn[i, 16h+j] q[16h+j]
        const int i = t & 127, p = t >> 7;
        #pragma unroll
        for (int u = 0; u < 2; ++u) {
            const int h = p + 4 * u;
            float a = 0.f;
            #pragma unroll
            for (int j = 0; j < 16; ++j)
                a = fmaf(Wn[i * 384 + h * 16 + j], s_q[h * 16 + j], a);
            qpt[(size_t)b * 1024 + h * 128 + i] = a * 0.25f;
        }
    }
}

// ---------------- KB: compat + local softmax + wembp, emb slice LDS-resident ----------------
// step1: compat (coalesced 4-rows-x-16-lanes) while teeing the slice into LDS;
// step2: local per-head max/raw-sum; step3: p = exp(c - m_loc) in place;
// step4: outer product from the LDS tile (no 2nd global read). Wave w owns
// output cols [16w,16w+16); lane (rg,c) strides rows; shfl_xor(16/32) reduce.
#define EST 132   // LDS row stride for the emb tile
__global__ __launch_bounds__(512, 4)
void kB_fused(const float* __restrict__ emb, const float* __restrict__ qpt,
              const void* __restrict__ maskp, const int* __restrict__ mflag,
              float* __restrict__ wembp, float* __restrict__ stats) {
    const int b = blockIdx.x >> 3, s = blockIdx.x & 7;
    const int t = threadIdx.x, w = t >> 6, lane = t & 63;
    const int rg = lane >> 4, cl = lane & 15;
    const float* eb = emb + (size_t)b * (NN * DD);
    __shared__ __align__(16) float s_qpT[1024];
    __shared__ __align__(16) float s_emb[125 * EST];   // 66 KB slice tile
    __shared__ __align__(16) float s_cp[128 * 8];      // compat -> p in place
    __shared__ float s_m[8], s_sum[8];
    for (int i = t; i < 1024; i += 512) s_qpT[i] = qpt[(size_t)b * 1024 + i];
    __syncthreads();
    float4 qa[8], qb[8];   // qproj cols cl*8..cl*8+7 for all 8 heads (64 VGPR)
    #pragma unroll
    for (int h = 0; h < 8; ++h) {
        qa[h] = *(const float4*)&s_qpT[h * 128 + cl * 8];
        qb[h] = *(const float4*)&s_qpT[h * 128 + cl * 8 + 4];
    }
    const int use32 = *mflag;
    const unsigned char* mk8 = (const unsigned char*)maskp + (size_t)b * NN;
    const int* mk32 = (const int*)maskp + (size_t)b * NN;
    // ---- step 1: compat into LDS + tee slice into s_emb ----
    #pragma unroll
    for (int it = 0; it < 4; ++it) {
        const int r = w * 16 + it * 4 + rg;     // 0..127
        const int n = s * 125 + r;
        float acc[8] = {0.f,0.f,0.f,0.f,0.f,0.f,0.f,0.f};
        if (r < 125) {
            const float4 e0 = *(const float4*)(eb + (size_t)n * DD + cl * 8);
            const float4 e1 = *(const float4*)(eb + (size_t)n * DD + cl * 8 + 4);
            *(float4*)&s_emb[r * EST + cl * 8]     = e0;
            *(float4*)&s_emb[r * EST + cl * 8 + 4] = e1;
            #pragma unroll
            for (int h = 0; h < 8; ++h) {
                float a = e0.x * qa[h].x;
                a = fmaf(e0.y, qa[h].y, a);
                a = fmaf(e0.z, qa[h].z, a);
                a = fmaf(e0.w, qa[h].w, a);
                a = fmaf(e1.x, qb[h].x, a);
                a = fmaf(e1.y, qb[h].y, a);
                a = fmaf(e1.z, qb[h].z, a);
                a = fmaf(e1.w, qb[h].w, a);
                acc[h] = a;
            }
        }
        #pragma unroll
        for (int h = 0; h < 8; ++h) {
            acc[h] += __shfl_xor(acc[h], 1, 16);
            acc[h] += __shfl_xor(acc[h], 2, 16);
            acc[h] += __shfl_xor(acc[h], 4, 16);
            acc[h] += __shfl_xor(acc[h], 8, 16);
        }
        if (cl == 0 && r < 125) {
            const bool m = use32 ? (mk32[n] != 0) : (mk8[n] != 0);
            float4 o0, o1;
            if (m) { o0 = make_float4(NEG_BIG, NEG_BIG, NEG_BIG, NEG_BIG); o1 = o0; }
            else   { o0 = make_float4(acc[0], acc[1], acc[2], acc[3]);
                     o1 = make_float4(acc[4], acc[5], acc[6], acc[7]); }
            *(float4*)&s_cp[r * 8]     = o0;
            *(float4*)&s_cp[r * 8 + 4] = o1;
        }
    }
    __syncthreads();
    // ---- step 2: local per-head max / raw sum (wave w = head w) ----
    {
        float m = NEG_BIG;
        for (int r = lane; r < 125; r += 64) m = fmaxf(m, s_cp[r * 8 + w]);
        #pragma unroll
        for (int o = 32; o; o >>= 1) m = fmaxf(m, __shfl_xor(m, o, 64));
        float sum = 0.f;
        for (int r = lane; r < 125; r += 64) sum += expf(s_cp[r * 8 + w] - m);
        #pragma unroll
        for (int o = 32; o; o >>= 1) sum += __shfl_xor(sum, o, 64);
        if (lane == 0) { s_m[w] = m; s_sum[w] = sum; }
    }
    __syncthreads();
    // ---- step 3: unnormalized p in place ----
    for (int idx = t; idx < 1000; idx += 512)
        s_cp[idx] = expf(s_cp[idx] - s_m[idx & 7]);
    __syncthreads();
    // ---- step 4: wembp from the LDS tile (no global re-read) ----
    {
        const int col = w * 16 + cl;
        float acc[8] = {0.f,0.f,0.f,0.f,0.f,0.f,0.f,0.f};
        for (int r = rg; r < 125; r += 4) {
            const float  e  = s_emb[r * EST + col];
            const float4 p0 = *(const float4*)&s_cp[r * 8];
            const float4 p1 = *(const float4*)&s_cp[r * 8 + 4];
            acc[0] = fmaf(e, p0.x, acc[0]);
            acc[1] = fmaf(e, p0.y, acc[1]);
            acc[2] = fmaf(e, p0.z, acc[2]);
            acc[3] = fmaf(e, p0.w, acc[3]);
            acc[4] = fmaf(e, p1.x, acc[4]);
            acc[5] = fmaf(e, p1.y, acc[5]);
            acc[6] = fmaf(e, p1.z, acc[6]);
            acc[7] = fmaf(e, p1.w, acc[7]);
        }
        #pragma unroll
        for (int h = 0; h < 8; ++h) {
            acc[h] += __shfl_xor(acc[h], 16, 64);
            acc[h] += __shfl_xor(acc[h], 32, 64);
        }
        if (rg == 0) {
            #pragma unroll
            for (int h = 0; h < 8; ++h)
                wembp[(size_t)b * 8192 + s * 1024 + h * 128 + col] = acc[h];
        }
    }
    if (t < 8)        stats[(size_t)b * 128 + s * 16 + t] = s_m[t];
    else if (t < 16)  stats[(size_t)b * 128 + s * 16 + t] = s_sum[t - 8];
}

// ---------------- K4a: rescale-merge -> wemb -> heads -> glimpse -> g2 ----------------
__global__ __launch_bounds__(512, 4)
void k4a_g2(const float* __restrict__ wembp, const float* __restrict__ stats,
            const float* __restrict__ Wn, const float* __restrict__ Wo,
            float* __restrict__ g2v) {
    const int b = blockIdx.x, t = threadIdx.x;
    __shared__ float s_w[8][8];
    __shared__ float s_wemb[8 * 130];
    __shared__ float s_red[512];
    __shared__ float s_heads[128], s_gl[128];
    if (t < 8) {
        const int h = t;
        float m = NEG_BIG;
        #pragma unroll
        for (int s = 0; s < 8; ++s) m = fmaxf(m, stats[(size_t)b * 128 + s * 16 + h]);
        float den = 0.f;
        #pragma unroll
        for (int s = 0; s < 8; ++s)
            den += stats[(size_t)b * 128 + s * 16 + 8 + h] * expf(stats[(size_t)b * 128 + s * 16 + h] - m);
        const float dinv = 1.0f / den;
        #pragma unroll
        for (int s = 0; s < 8; ++s)
            s_w[s][h] = expf(stats[(size_t)b * 128 + s * 16 + h] - m) * dinv;
    }
    __syncthreads();
    for (int idx = t; idx < 1024; idx += 512) {
        const int h = idx >> 7, i = idx & 127;
        float v = 0.f;
        #pragma unroll
        for (int s = 0; s < 8; ++s) v += wembp[(size_t)b * 8192 + s * 1024 + idx] * s_w[s][h];
        s_wemb[h * 130 + i] = v;
    }
    __syncthreads();
    {   // heads[j] = sum_i Wv[i,j] wemb[j>>4][i]
        const int j = t & 127, p = t >> 7;
        float a = 0.f;
        for (int i = 32 * p; i < 32 * p + 32; ++i)
            a = fmaf(Wn[i * 384 + 128 + j], s_wemb[(j >> 4) * 130 + i], a);
        s_red[p * 128 + j] = a;
    }
    __syncthreads();
    if (t < 128) s_heads[t] = s_red[t] + s_red[128 + t] + s_red[256 + t] + s_red[384 + t];
    __syncthreads();
    {   // glimpse[d] = sum_j heads[j] Wo[j,d]
        const int d = t & 127, p = t >> 7;
        float a = 0.f;
        for (int j = 32 * p; j < 32 * p + 32; ++j)
            a = fmaf(s_heads[j], Wo[j * DD + d], a);
        s_red[p * 128 + d] = a;
    }
    __syncthreads();
    if (t < 128) s_gl[t] = s_red[t] + s_red[128 + t] + s_red[256 + t] + s_red[384 + t];
    __syncthreads();
    {   // g2[i] = (1/sqrt(128)) sum_d Wl[i,d] glimpse[d]
        const int i = t & 127, p = t >> 7;
        float a = 0.f;
        for (int d = 32 * p; d < 32 * p + 32; ++d)
            a = fmaf(Wn[i * 384 + 256 + d], s_gl[d], a);
        s_red[p * 128 + i] = a;
    }
    __syncthreads();
    if (t < 128)
        g2v[(size_t)b * 128 + t] =
            (s_red[t] + s_red[128 + t] + s_red[256 + t] + s_red[384 + t]) * 0.08838834764831845f;
}

// ---------------- K4b: logits, coalesced 4-rows-x-16-lanes ----------------
__global__ __launch_bounds__(512, 2)
void k4b_logits(const float* __restrict__ emb, const float* __restrict__ g2v,
                const void* __restrict__ maskp, const int* __restrict__ mflag,
                float* __restrict__ logits) {
    const int b = blockIdx.x >> 3, s = blockIdx.x & 7;
    const int t = threadIdx.x, w = t >> 6, lane = t & 63;
    const int rg = lane >> 4, cl = lane & 15;
    const float* eb = emb + (size_t)b * (NN * DD);
    __shared__ __align__(16) float s_g2[128];
    if (t < 128) s_g2[t] = g2v[(size_t)b * 128 + t];
    __syncthreads();
    const float4 ga = *(const float4*)&s_g2[cl * 8];
    const float4 gb = *(const float4*)&s_g2[cl * 8 + 4];
    const int use32 = *mflag;
    const unsigned char* mk8 = (const unsigned char*)maskp + (size_t)b * NN;
    const int* mk32 = (const int*)maskp + (size_t)b * NN;
    #pragma unroll
    for (int it = 0; it < 4; ++it) {
        const int r = w * 16 + it * 4 + rg;
        const int n = s * 125 + r;
        float a = 0.f;
        if (r < 125) {
            const float4 e0 = *(const float4*)(eb + (size_t)n * DD + cl * 8);
            const float4 e1 = *(const float4*)(eb + (size_t)n * DD + cl * 8 + 4);
            a = e0.x * ga.x;
            a = fmaf(e0.y, ga.y, a);
            a = fmaf(e0.z, ga.z, a);
            a = fmaf(e0.w, ga.w, a);
            a = fmaf(e1.x, gb.x, a);
            a = fmaf(e1.y, gb.y, a);
            a = fmaf(e1.z, gb.z, a);
            a = fmaf(e1.w, gb.w, a);
        }
        a += __shfl_xor(a, 1, 16);
        a += __shfl_xor(a, 2, 16);
        a += __shfl_xor(a, 4, 16);
        a += __shfl_xor(a, 8, 16);
        if (cl == 0 && r < 125) {
            const bool m = use32 ? (mk32[n] != 0) : (mk8[n] != 0);
            logits[(size_t)b * 1024 + n] = m ? NEG_BIG : 10.0f * tanhf(a);
        }
    }
}

// ---------------- K5: per-batch log_softmax ----------------
__global__ __launch_bounds__(512, 4)
void k5_logsoftmax(const float* __restrict__ logits, float* __restrict__ out) {
    const int b = blockIdx.x, t = threadIdx.x, w = t >> 6, lane = t & 63;
    __shared__ float s_red[16];
    __shared__ float s_lse;
    const float* lg = logits + (size_t)b * 1024;
    float m = NEG_BIG;
    for (int n = t; n < NN; n += 512) m = fmaxf(m, lg[n]);
    #pragma unroll
    for (int o = 32; o; o >>= 1) m = fmaxf(m, __shfl_xor(m, o, 64));
    if (lane == 0) s_red[w] = m;
    __syncthreads();
    if (t == 0) {
        float mm = s_red[0];
        #pragma unroll
        for (int i = 1; i < 8; ++i) mm = fmaxf(mm, s_red[i]);
        s_red[8] = mm;
    }
    __syncthreads();
    const float mb = s_red[8];
    float sum = 0.f;
    for (int n = t; n < NN; n += 512) sum += expf(lg[n] - mb);
    #pragma unroll
    for (int o = 32; o; o >>= 1) sum += __shfl_xor(sum, o, 64);
    __syncthreads();
    if (lane == 0) s_red[w] = sum;
    __syncthreads();
    if (t == 0) {
        float ss = 0.f;
        #pragma unroll
        for (int i = 0; i < 8; ++i) ss += s_red[i];
        s_lse = mb + logf(ss);
    }
    __syncthreads();
    const float lse = s_lse;
    float* ob = out + (size_t)b * NN;
    for (int n = t; n < NN; n += 512) ob[n] = lg[n] - lse;
}

extern "C" void kernel_launch(void* const* d_in, const int* in_sizes, int n_in,
                              void* d_out, int out_size, void* d_ws, size_t ws_size,
                              hipStream_t stream) {
    const float* emb   = (const float*)d_in[0];
    const float* stepc = (const float*)d_in[1];
    const void*  mask  = (const void*)d_in[2];
    const float* Wn = (const float*)d_in[3];
    const float* Wf = (const float*)d_in[4];
    const float* Ws = (const float*)d_in[5];
    const float* Wo = (const float*)d_in[6];
    float* out = (float*)d_out;
    const int B = in_sizes[0] / (NN * DD);  // 256

    float* wsf = (float*)d_ws;
    const size_t n_meanp = (size_t)B * 1024;
    const size_t n_qpt   = (size_t)B * 1024;
    const size_t n_wembp = (size_t)B * 8192;
    const size_t n_g2    = (size_t)B * 128;
    const size_t n_stats = (size_t)B * 128;
    const size_t n_logit = (size_t)B * 1024;

    float* meanp  = wsf;
    float* qpt    = meanp + n_meanp;
    float* wembp  = qpt + n_qpt;
    float* g2v    = wembp + n_wembp;
    float* stats  = g2v + n_g2;
    float* logits = stats + n_stats;
    int*   mflag  = (int*)(logits + n_logit);

    k1_meanpart  <<<B * 8, 256, 0, stream>>>(emb, meanp);
    k1b_qproj    <<<B,     512, 0, stream>>>(meanp, stepc, mask, Wn, Wf, Ws, qpt, mflag);
    kB_fused     <<<B * 8, 512, 0, stream>>>(emb, qpt, mask, mflag, wembp, stats);
    k4a_g2       <<<B,     512, 0, stream>>>(wembp, stats, Wn, Wo, g2v);
    k4b_logits   <<<B * 8, 512, 0, stream>>>(emb, g2v, mask, mflag, logits);
    k5_logsoftmax<<<B,     512, 0, stream>>>(logits, out);
}

// Round 8
// 119.854 us; speedup vs baseline: 9.2146x; 1.0850x over previous
//
#include <hip/hip_runtime.h>
#include <math.h>

#define NN   1000
#define DD   128
#define CTXN 130
#define NEG_BIG (-1.0e30f)

// ============================================================================
// 3-dispatch pipeline (3 forced emb passes, minimal launch/small-kernel cost):
//  K1' (B blk x1024): emb slab -> mean -> query -> qproj[h][i] (+mask probe)
//  kB  (B*8 x512)   : compat -> local max/sum -> wembp_s (slice LDS-resident)
//  K4' (B blk x1024): merge -> heads -> glimpse -> g2 -> logits -> log_softmax
// ws: qpt[B][1024] | wembp[B][8192] | stats[B][128] | mflag
// ============================================================================

// ---------------- K1': mean + query + qproj, one block per batch ----------------
__global__ __launch_bounds__(1024, 4)
void k1_fused(const float* __restrict__ emb, const float* __restrict__ stepc,
              const void* __restrict__ maskp,
              const float* __restrict__ Wn, const float* __restrict__ Wf,
              const float* __restrict__ Ws,
              float* __restrict__ qpt, int* __restrict__ mflag) {
    const int b = blockIdx.x, t = threadIdx.x;
    const float* eb = emb + (size_t)b * (NN * DD);
    __shared__ __align__(16) float S[4096];   // 16 KB reduction scratch
    __shared__ float s_mean[128], s_q[128];
    if (b == 0 && t == 0) {   // mask layout probe (int32: bytes 1 mod 4 all 0)
        const unsigned char* mb8 = (const unsigned char*)maskp;
        int any = 0;
        for (int k = 0; k < 64; ++k) any |= mb8[4 * k + 1];
        *mflag = (any == 0) ? 1 : 0;
    }
    // ---- mean: 32 row-groups x 32 float4-columns ----
    {
        const int c4 = t & 31, g = t >> 5;    // g in [0,32)
        float4 a = make_float4(0.f, 0.f, 0.f, 0.f);
        for (int r = g; r < NN; r += 32) {
            const float4 v = *(const float4*)(eb + (size_t)r * DD + c4 * 4);
            a.x += v.x; a.y += v.y; a.z += v.z; a.w += v.w;
        }
        ((float4*)S)[g * 32 + c4] = a;        // S[g][c] floats
    }
    __syncthreads();
    if (t < 128) {
        float v = 0.f;
        #pragma unroll
        for (int g = 0; g < 32; ++g) v += S[g * 128 + t];
        s_mean[t] = v * (1.0f / (float)NN);
    }
    __syncthreads();
    // ---- query[d] = mean.Wf[:,d] + sc.Ws[:,d], 8-way split ----
    {
        const int d = t & 127, p = t >> 7;    // p in [0,8)
        float a = 0.f;
        for (int i = 16 * p; i < 16 * p + 16; ++i)
            a = fmaf(s_mean[i], Wf[i * DD + d], a);
        const float* scb = stepc + (size_t)b * CTXN;
        const int c0 = 16 * p, c1 = (p == 7) ? CTXN : 16 * p + 16;
        for (int c = c0; c < c1; ++c)
            a = fmaf(scb[c], Ws[c * DD + d], a);
        S[p * 128 + d] = a;
    }
    __syncthreads();
    if (t < 128) {
        float v = 0.f;
        #pragma unroll
        for (int p = 0; p < 8; ++p) v += S[p * 128 + t];
        s_q[t] = v;
    }
    __syncthreads();
    // ---- qproj: thread (i = t&127, h = t>>7) one-shot ----
    {
        const int i = t & 127, h = t >> 7;
        float a = 0.f;
        #pragma unroll
        for (int j = 0; j < 16; ++j)
            a = fmaf(Wn[i * 384 + h * 16 + j], s_q[h * 16 + j], a);
        qpt[(size_t)b * 1024 + h * 128 + i] = a * 0.25f;  // 1/sqrt(16)
    }
}

// ---------------- KB: compat + local softmax + wembp, emb slice LDS-resident ----------------
#define EST 132
__global__ __launch_bounds__(512, 4)
void kB_fused(const float* __restrict__ emb, const float* __restrict__ qpt,
              const void* __restrict__ maskp, const int* __restrict__ mflag,
              float* __restrict__ wembp, float* __restrict__ stats) {
    const int b = blockIdx.x >> 3, s = blockIdx.x & 7;
    const int t = threadIdx.x, w = t >> 6, lane = t & 63;
    const int rg = lane >> 4, cl = lane & 15;
    const float* eb = emb + (size_t)b * (NN * DD);
    __shared__ __align__(16) float s_qpT[1024];
    __shared__ __align__(16) float s_emb[125 * EST];   // 66 KB slice tile
    __shared__ __align__(16) float s_cp[128 * 8];      // compat -> p in place
    __shared__ float s_m[8], s_sum[8];
    for (int i = t; i < 1024; i += 512) s_qpT[i] = qpt[(size_t)b * 1024 + i];
    __syncthreads();
    float4 qa[8], qb[8];
    #pragma unroll
    for (int h = 0; h < 8; ++h) {
        qa[h] = *(const float4*)&s_qpT[h * 128 + cl * 8];
        qb[h] = *(const float4*)&s_qpT[h * 128 + cl * 8 + 4];
    }
    const int use32 = *mflag;
    const unsigned char* mk8 = (const unsigned char*)maskp + (size_t)b * NN;
    const int* mk32 = (const int*)maskp + (size_t)b * NN;
    #pragma unroll
    for (int it = 0; it < 4; ++it) {
        const int r = w * 16 + it * 4 + rg;
        const int n = s * 125 + r;
        float acc[8] = {0.f,0.f,0.f,0.f,0.f,0.f,0.f,0.f};
        if (r < 125) {
            const float4 e0 = *(const float4*)(eb + (size_t)n * DD + cl * 8);
            const float4 e1 = *(const float4*)(eb + (size_t)n * DD + cl * 8 + 4);
            *(float4*)&s_emb[r * EST + cl * 8]     = e0;
            *(float4*)&s_emb[r * EST + cl * 8 + 4] = e1;
            #pragma unroll
            for (int h = 0; h < 8; ++h) {
                float a = e0.x * qa[h].x;
                a = fmaf(e0.y, qa[h].y, a);
                a = fmaf(e0.z, qa[h].z, a);
                a = fmaf(e0.w, qa[h].w, a);
                a = fmaf(e1.x, qb[h].x, a);
                a = fmaf(e1.y, qb[h].y, a);
                a = fmaf(e1.z, qb[h].z, a);
                a = fmaf(e1.w, qb[h].w, a);
                acc[h] = a;
            }
        }
        #pragma unroll
        for (int h = 0; h < 8; ++h) {
            acc[h] += __shfl_xor(acc[h], 1, 16);
            acc[h] += __shfl_xor(acc[h], 2, 16);
            acc[h] += __shfl_xor(acc[h], 4, 16);
            acc[h] += __shfl_xor(acc[h], 8, 16);
        }
        if (cl == 0 && r < 125) {
            const bool m = use32 ? (mk32[n] != 0) : (mk8[n] != 0);
            float4 o0, o1;
            if (m) { o0 = make_float4(NEG_BIG, NEG_BIG, NEG_BIG, NEG_BIG); o1 = o0; }
            else   { o0 = make_float4(acc[0], acc[1], acc[2], acc[3]);
                     o1 = make_float4(acc[4], acc[5], acc[6], acc[7]); }
            *(float4*)&s_cp[r * 8]     = o0;
            *(float4*)&s_cp[r * 8 + 4] = o1;
        }
    }
    __syncthreads();
    {   // local per-head max / raw sum (wave w = head w)
        float m = NEG_BIG;
        for (int r = lane; r < 125; r += 64) m = fmaxf(m, s_cp[r * 8 + w]);
        #pragma unroll
        for (int o = 32; o; o >>= 1) m = fmaxf(m, __shfl_xor(m, o, 64));
        float sum = 0.f;
        for (int r = lane; r < 125; r += 64) sum += expf(s_cp[r * 8 + w] - m);
        #pragma unroll
        for (int o = 32; o; o >>= 1) sum += __shfl_xor(sum, o, 64);
        if (lane == 0) { s_m[w] = m; s_sum[w] = sum; }
    }
    __syncthreads();
    for (int idx = t; idx < 1000; idx += 512)
        s_cp[idx] = expf(s_cp[idx] - s_m[idx & 7]);
    __syncthreads();
    {   // wembp from LDS tile: wave w owns cols [16w,16w+16), shfl(16/32) reduce
        const int col = w * 16 + cl;
        float acc[8] = {0.f,0.f,0.f,0.f,0.f,0.f,0.f,0.f};
        for (int r = rg; r < 125; r += 4) {
            const float  e  = s_emb[r * EST + col];
            const float4 p0 = *(const float4*)&s_cp[r * 8];
            const float4 p1 = *(const float4*)&s_cp[r * 8 + 4];
            acc[0] = fmaf(e, p0.x, acc[0]);
            acc[1] = fmaf(e, p0.y, acc[1]);
            acc[2] = fmaf(e, p0.z, acc[2]);
            acc[3] = fmaf(e, p0.w, acc[3]);
            acc[4] = fmaf(e, p1.x, acc[4]);
            acc[5] = fmaf(e, p1.y, acc[5]);
            acc[6] = fmaf(e, p1.z, acc[6]);
            acc[7] = fmaf(e, p1.w, acc[7]);
        }
        #pragma unroll
        for (int h = 0; h < 8; ++h) {
            acc[h] += __shfl_xor(acc[h], 16, 64);
            acc[h] += __shfl_xor(acc[h], 32, 64);
        }
        if (rg == 0) {
            #pragma unroll
            for (int h = 0; h < 8; ++h)
                wembp[(size_t)b * 8192 + s * 1024 + h * 128 + col] = acc[h];
        }
    }
    if (t < 8)        stats[(size_t)b * 128 + s * 16 + t] = s_m[t];
    else if (t < 16)  stats[(size_t)b * 128 + s * 16 + t] = s_sum[t - 8];
}

// ---------------- K4': merge -> g2 -> logits -> log_softmax, one block per batch ----------------
__global__ __launch_bounds__(1024, 4)
void k4_fused(const float* __restrict__ emb, const float* __restrict__ wembp,
              const float* __restrict__ stats,
              const float* __restrict__ Wn, const float* __restrict__ Wo,
              const void* __restrict__ maskp, const int* __restrict__ mflag,
              float* __restrict__ out) {
    const int b = blockIdx.x, t = threadIdx.x;
    const int w = t >> 6, lane = t & 63;
    const int rg = lane >> 4, cl = lane & 15;
    const float* eb = emb + (size_t)b * (NN * DD);
    __shared__ float s_w[64];            // [s][h]
    __shared__ float s_wemb[8 * 130];
    __shared__ __align__(16) float s_red[1024];
    __shared__ float s_h[128], s_gl[128], s_g2[128];
    __shared__ float s_logits[1000];
    __shared__ float s_r2[32];
    __shared__ float s_lse;
    // ---- merge weights ----
    if (t < 8) {
        const int h = t;
        float m = NEG_BIG;
        #pragma unroll
        for (int s = 0; s < 8; ++s) m = fmaxf(m, stats[(size_t)b * 128 + s * 16 + h]);
        float den = 0.f;
        #pragma unroll
        for (int s = 0; s < 8; ++s)
            den += stats[(size_t)b * 128 + s * 16 + 8 + h] * expf(stats[(size_t)b * 128 + s * 16 + h] - m);
        const float dinv = 1.0f / den;
        #pragma unroll
        for (int s = 0; s < 8; ++s)
            s_w[s * 8 + h] = expf(stats[(size_t)b * 128 + s * 16 + h] - m) * dinv;
    }
    __syncthreads();
    {   // wemb[h][i]: one shot (t = h*128+i)
        const int h = t >> 7, i = t & 127;
        float v = 0.f;
        #pragma unroll
        for (int s = 0; s < 8; ++s)
            v += wembp[(size_t)b * 8192 + s * 1024 + t] * s_w[s * 8 + h];
        s_wemb[h * 130 + i] = v;
    }
    __syncthreads();
    {   // heads[j] = sum_i Wv[i,j] wemb[j>>4][i], 8-way i-split
        const int j = t & 127, p = t >> 7;
        float a = 0.f;
        for (int i = 16 * p; i < 16 * p + 16; ++i)
            a = fmaf(Wn[i * 384 + 128 + j], s_wemb[(j >> 4) * 130 + i], a);
        s_red[p * 128 + j] = a;
    }
    __syncthreads();
    if (t < 128) {
        float v = 0.f;
        #pragma unroll
        for (int p = 0; p < 8; ++p) v += s_red[p * 128 + t];
        s_h[t] = v;
    }
    __syncthreads();
    {   // glimpse[d] = sum_j heads[j] Wo[j,d]
        const int d = t & 127, p = t >> 7;
        float a = 0.f;
        for (int j = 16 * p; j < 16 * p + 16; ++j)
            a = fmaf(s_h[j], Wo[j * DD + d], a);
        s_red[p * 128 + d] = a;
    }
    __syncthreads();
    if (t < 128) {
        float v = 0.f;
        #pragma unroll
        for (int p = 0; p < 8; ++p) v += s_red[p * 128 + t];
        s_gl[t] = v;
    }
    __syncthreads();
    {   // g2[i] = (1/sqrt(128)) sum_d Wl[i,d] glimpse[d]
        const int i = t & 127, p = t >> 7;
        float a = 0.f;
        for (int d = 16 * p; d < 16 * p + 16; ++d)
            a = fmaf(Wn[i * 384 + 256 + d], s_gl[d], a);
        s_red[p * 128 + i] = a;
    }
    __syncthreads();
    if (t < 128) {
        float v = 0.f;
        #pragma unroll
        for (int p = 0; p < 8; ++p) v += s_red[p * 128 + t];
        s_g2[t] = v * 0.08838834764831845f;
    }
    __syncthreads();
    // ---- logits: 16 waves x 4-rows-x-16-lanes, coalesced ----
    {
        const float4 ga = *(const float4*)&s_g2[cl * 8];
        const float4 gb = *(const float4*)&s_g2[cl * 8 + 4];
        const int use32 = *mflag;
        const unsigned char* mk8 = (const unsigned char*)maskp + (size_t)b * NN;
        const int* mk32 = (const int*)maskp + (size_t)b * NN;
        for (int it = 0; it < 16; ++it) {
            const int n = it * 64 + w * 4 + rg;   // 0..1023
            float a = 0.f;
            if (n < NN) {
                const float4 e0 = *(const float4*)(eb + (size_t)n * DD + cl * 8);
                const float4 e1 = *(const float4*)(eb + (size_t)n * DD + cl * 8 + 4);
                a = e0.x * ga.x;
                a = fmaf(e0.y, ga.y, a);
                a = fmaf(e0.z, ga.z, a);
                a = fmaf(e0.w, ga.w, a);
                a = fmaf(e1.x, gb.x, a);
                a = fmaf(e1.y, gb.y, a);
                a = fmaf(e1.z, gb.z, a);
                a = fmaf(e1.w, gb.w, a);
            }
            a += __shfl_xor(a, 1, 16);
            a += __shfl_xor(a, 2, 16);
            a += __shfl_xor(a, 4, 16);
            a += __shfl_xor(a, 8, 16);
            if (cl == 0 && n < NN) {
                const bool m = use32 ? (mk32[n] != 0) : (mk8[n] != 0);
                s_logits[n] = m ? NEG_BIG : 10.0f * tanhf(a);
            }
        }
    }
    __syncthreads();
    // ---- log_softmax ----
    {
        float m = NEG_BIG;
        if (t < NN) m = s_logits[t];
        #pragma unroll
        for (int o = 32; o; o >>= 1) m = fmaxf(m, __shfl_xor(m, o, 64));
        if (lane == 0) s_r2[w] = m;
        __syncthreads();
        if (t == 0) {
            float mm = s_r2[0];
            #pragma unroll
            for (int i = 1; i < 16; ++i) mm = fmaxf(mm, s_r2[i]);
            s_r2[16] = mm;
        }
        __syncthreads();
        const float mb = s_r2[16];
        float sum = (t < NN) ? expf(s_logits[t] - mb) : 0.f;
        #pragma unroll
        for (int o = 32; o; o >>= 1) sum += __shfl_xor(sum, o, 64);
        __syncthreads();
        if (lane == 0) s_r2[w] = sum;
        __syncthreads();
        if (t == 0) {
            float ss = 0.f;
            #pragma unroll
            for (int i = 0; i < 16; ++i) ss += s_r2[i];
            s_lse = mb + logf(ss);
        }
        __syncthreads();
        if (t < NN) out[(size_t)b * NN + t] = s_logits[t] - s_lse;
    }
}

extern "C" void kernel_launch(void* const* d_in, const int* in_sizes, int n_in,
                              void* d_out, int out_size, void* d_ws, size_t ws_size,
                              hipStream_t stream) {
    const float* emb   = (const float*)d_in[0];
    const float* stepc = (const float*)d_in[1];
    const void*  mask  = (const void*)d_in[2];
    const float* Wn = (const float*)d_in[3];
    const float* Wf = (const float*)d_in[4];
    const float* Ws = (const float*)d_in[5];
    const float* Wo = (const float*)d_in[6];
    float* out = (float*)d_out;
    const int B = in_sizes[0] / (NN * DD);  // 256

    float* wsf = (float*)d_ws;
    const size_t n_qpt   = (size_t)B * 1024;
    const size_t n_wembp = (size_t)B * 8192;
    const size_t n_stats = (size_t)B * 128;

    float* qpt   = wsf;
    float* wembp = qpt + n_qpt;
    float* stats = wembp + n_wembp;
    int*   mflag = (int*)(stats + n_stats);

    k1_fused<<<B,     1024, 0, stream>>>(emb, stepc, mask, Wn, Wf, Ws, qpt, mflag);
    kB_fused<<<B * 8, 512,  0, stream>>>(emb, qpt, mask, mflag, wembp, stats);
    k4_fused<<<B,     1024, 0, stream>>>(emb, wembp, stats, Wn, Wo, mask, mflag, out);
}